// Round 1
// baseline (1499.156 us; speedup 1.0000x reference)
//
#include <hip/hip_runtime.h>

#define N_ 16384
#define D_ 256
#define KSPLIT 2
#define KPER (N_ / KSPLIT)   // 8192
#define BK 64
#define BM 64

typedef __attribute__((ext_vector_type(8))) short short8_t;    // 8 bf16
typedef __attribute__((ext_vector_type(4))) short short4_t;    // 4 bf16
typedef __attribute__((ext_vector_type(4))) float f32x4;
typedef __attribute__((ext_vector_type(4))) unsigned int u32x4;

// fp32 -> bf16 round-to-nearest-even (bit manip; no hip_bf16 struct overhead)
static __device__ __forceinline__ short f2bf(float f) {
  unsigned int u = __float_as_uint(f);
  u += 0x7fffu + ((u >> 16) & 1u);
  return (short)(u >> 16);
}

// ---------------------------------------------------------------------------
// Kernel 1: featT[n][k] = bf16(feat[k][n])  (tiled transpose)  +  Wb = bf16(W)
// ---------------------------------------------------------------------------
__global__ __launch_bounds__(256)
void k_prep(const float* __restrict__ feat, const float* __restrict__ W,
            short* __restrict__ featT, short* __restrict__ Wb) {
  int b = blockIdx.x;
  int t = threadIdx.x;
  if (b < 1024) {
    __shared__ short tile[64][65];   // +1 pad: conflict-free transposed reads
    int tk = b >> 2, tn = b & 3;
    int k0 = tk * 64, n0 = tn * 64;
    int c = t & 63, rb = t >> 6;
#pragma unroll
    for (int i = 0; i < 16; ++i) {
      int r = rb + i * 4;
      tile[r][c] = f2bf(feat[(k0 + r) * D_ + n0 + c]);
    }
    __syncthreads();
#pragma unroll
    for (int i = 0; i < 16; ++i) {
      int r = rb + i * 4;
      featT[(long)(n0 + r) * N_ + k0 + c] = tile[c][r];
    }
  } else {
    int base = (b - 1024) * 256 + t;   // 32 blocks cover 256*512 = 131072 elems
#pragma unroll
    for (int i = 0; i < 16; ++i) {
      int idx = base + i * 8192;
      Wb[idx] = f2bf(W[idx]);
    }
  }
}

// ---------------------------------------------------------------------------
// Kernel 2: partial[s] = adj[:, ks] @ feat[ks, :]  (bf16 MFMA, fp32 acc)
//           degp[s][m] = rowsum(adj[m, ks])  -- fused into the staging pass
// block: 256 thr / 4 waves; tile BM=64 rows x 256 cols; wave w -> cols w*64..
// ---------------------------------------------------------------------------
__global__ __launch_bounds__(256, 2)
void k_main(const float* __restrict__ adj, const short* __restrict__ featT,
            float* __restrict__ part, float* __restrict__ degp) {
  __shared__ short At[BM * BK];    // [m][kk], 128 B rows
  __shared__ short Bt[D_ * BK];    // [n][kk], 128 B rows
  int tid = threadIdx.x;
  int w = tid >> 6, lane = tid & 63;
  int q = lane >> 4, ml = lane & 15;
  int m0 = blockIdx.x * BM;
  int s = blockIdx.y;
  long kbase = (long)s * KPER;

  f32x4 acc[4][4];
#pragma unroll
  for (int i = 0; i < 4; ++i)
#pragma unroll
    for (int j = 0; j < 4; ++j)
#pragma unroll
      for (int r = 0; r < 4; ++r) acc[i][j][r] = 0.f;

  int ar = tid >> 2;               // adj row 0..63 (4 threads/row)
  int ac = (tid & 3) * 16;         // 16 contiguous fp32 per thread
  const float* adjp = adj + (long)(m0 + ar) * N_ + kbase + ac;
  int fr = tid >> 3, fc = tid & 7; // featT staging: 8 rows/pass, 8 thr/row
  const short* featp = featT + (long)fr * N_ + kbase + fc * 8;

  float rowsum = 0.f;

  for (int it = 0; it < KPER / BK; ++it) {
    // -------- stage: global loads (adj fp32 + featT bf16) --------
    f32x4 v0 = *(const f32x4*)(adjp);
    f32x4 v1 = *(const f32x4*)(adjp + 4);
    f32x4 v2 = *(const f32x4*)(adjp + 8);
    f32x4 v3 = *(const f32x4*)(adjp + 12);
    adjp += BK;
    u32x4 fv[8];
#pragma unroll
    for (int i = 0; i < 8; ++i)
      fv[i] = *(const u32x4*)(featp + (long)i * 32 * N_);
    featp += BK;

    // fused degree partial (uses the adj values already in registers)
    rowsum += v0[0] + v0[1] + v0[2] + v0[3] + v1[0] + v1[1] + v1[2] + v1[3] +
              v2[0] + v2[1] + v2[2] + v2[3] + v3[0] + v3[1] + v3[2] + v3[3];

    short8_t pa, pb;
    pa[0] = f2bf(v0[0]); pa[1] = f2bf(v0[1]); pa[2] = f2bf(v0[2]); pa[3] = f2bf(v0[3]);
    pa[4] = f2bf(v1[0]); pa[5] = f2bf(v1[1]); pa[6] = f2bf(v1[2]); pa[7] = f2bf(v1[3]);
    pb[0] = f2bf(v2[0]); pb[1] = f2bf(v2[1]); pb[2] = f2bf(v2[2]); pb[3] = f2bf(v2[3]);
    pb[4] = f2bf(v3[0]); pb[5] = f2bf(v3[1]); pb[6] = f2bf(v3[2]); pb[7] = f2bf(v3[3]);

    *(short8_t*)&At[ar * BK + ac]     = pa;
    *(short8_t*)&At[ar * BK + ac + 8] = pb;
#pragma unroll
    for (int i = 0; i < 8; ++i)
      *(u32x4*)&Bt[(i * 32 + fr) * BK + fc * 8] = fv[i];

    __syncthreads();

    // -------- compute: 2 ksteps x 16 MFMAs per wave --------
#pragma unroll
    for (int ks = 0; ks < 2; ++ks) {
      short8_t a[4], bb[4];
#pragma unroll
      for (int i = 0; i < 4; ++i)
        a[i] = *(const short8_t*)&At[(i * 16 + ml) * BK + ks * 32 + q * 8];
#pragma unroll
      for (int j = 0; j < 4; ++j)
        bb[j] = *(const short8_t*)&Bt[(w * 64 + j * 16 + ml) * BK + ks * 32 + q * 8];
#pragma unroll
      for (int i = 0; i < 4; ++i)
#pragma unroll
        for (int j = 0; j < 4; ++j)
          acc[i][j] = __builtin_amdgcn_mfma_f32_16x16x32_bf16(a[i], bb[j], acc[i][j], 0, 0, 0);
    }
    __syncthreads();
  }

  // degree partial: reduce the 4 threads sharing a row (adjacent lanes)
  float rs = rowsum;
  rs += __shfl_xor(rs, 1);
  rs += __shfl_xor(rs, 2);
  if ((tid & 3) == 0) degp[s * N_ + m0 + ar] = rs;

  // store fp32 partial (C/D layout: col=lane&15, row=quad*4+reg  [m89-verified])
  float* pp = part + (long)s * N_ * D_ + (long)m0 * D_ + w * 64;
#pragma unroll
  for (int i = 0; i < 4; ++i)
#pragma unroll
    for (int j = 0; j < 4; ++j)
#pragma unroll
      for (int r = 0; r < 4; ++r)
        pp[(i * 16 + q * 4 + r) * D_ + j * 16 + ml] = acc[i][j][r];
}

// ---------------------------------------------------------------------------
// Kernel 3: neigh = bf16((part0 + part1) / (deg0 + deg1 + 1))
// ---------------------------------------------------------------------------
__global__ __launch_bounds__(256)
void k_combine(const float* __restrict__ part, const float* __restrict__ degp,
               short* __restrict__ neighRM) {
  long idx = ((long)blockIdx.x * 256 + threadIdx.x) * 4;
  int m = (int)(idx >> 8);
  float inv = 1.0f / (degp[m] + degp[N_ + m] + 1.0f);
  f32x4 p0 = *(const f32x4*)(part + idx);
  f32x4 p1 = *(const f32x4*)(part + (long)N_ * D_ + idx);
  short4_t o;
#pragma unroll
  for (int r = 0; r < 4; ++r) o[r] = f2bf((p0[r] + p1[r]) * inv);
  *(short4_t*)(neighRM + idx) = o;
}

// ---------------------------------------------------------------------------
// Kernel 4: out[16384][256] = [feat | neigh] @ W.T   (K=512, bf16 MFMA)
// iters 0-3 stage A from fp32 feat (convert), iters 4-7 from bf16 neigh
// ---------------------------------------------------------------------------
__global__ __launch_bounds__(256, 2)
void k_out(const float* __restrict__ feat, const short* __restrict__ neighRM,
           const short* __restrict__ Wb, float* __restrict__ out) {
  __shared__ short At[BM * BK];
  __shared__ short Bt[D_ * BK];
  int tid = threadIdx.x;
  int w = tid >> 6, lane = tid & 63;
  int q = lane >> 4, ml = lane & 15;
  int m0 = blockIdx.x * BM;

  f32x4 acc[4][4];
#pragma unroll
  for (int i = 0; i < 4; ++i)
#pragma unroll
    for (int j = 0; j < 4; ++j)
#pragma unroll
      for (int r = 0; r < 4; ++r) acc[i][j][r] = 0.f;

  int ar = tid >> 2, ac = (tid & 3) * 16;
  int fr = tid >> 3, fc = tid & 7;

  for (int it = 0; it < 8; ++it) {
    int k0 = it * BK;
    short8_t pa, pb;
    if (it < 4) {
      const float* src = feat + (long)(m0 + ar) * D_ + k0 + ac;
      f32x4 v0 = *(const f32x4*)(src);
      f32x4 v1 = *(const f32x4*)(src + 4);
      f32x4 v2 = *(const f32x4*)(src + 8);
      f32x4 v3 = *(const f32x4*)(src + 12);
      pa[0] = f2bf(v0[0]); pa[1] = f2bf(v0[1]); pa[2] = f2bf(v0[2]); pa[3] = f2bf(v0[3]);
      pa[4] = f2bf(v1[0]); pa[5] = f2bf(v1[1]); pa[6] = f2bf(v1[2]); pa[7] = f2bf(v1[3]);
      pb[0] = f2bf(v2[0]); pb[1] = f2bf(v2[1]); pb[2] = f2bf(v2[2]); pb[3] = f2bf(v2[3]);
      pb[4] = f2bf(v3[0]); pb[5] = f2bf(v3[1]); pb[6] = f2bf(v3[2]); pb[7] = f2bf(v3[3]);
    } else {
      const short* src = neighRM + (long)(m0 + ar) * D_ + (k0 - 256) + ac;
      pa = *(const short8_t*)(src);
      pb = *(const short8_t*)(src + 8);
    }
    u32x4 bv[8];
#pragma unroll
    for (int i = 0; i < 8; ++i)
      bv[i] = *(const u32x4*)(Wb + (i * 32 + fr) * 512 + k0 + fc * 8);

    *(short8_t*)&At[ar * BK + ac]     = pa;
    *(short8_t*)&At[ar * BK + ac + 8] = pb;
#pragma unroll
    for (int i = 0; i < 8; ++i)
      *(u32x4*)&Bt[(i * 32 + fr) * BK + fc * 8] = bv[i];

    __syncthreads();

#pragma unroll
    for (int ks = 0; ks < 2; ++ks) {
      short8_t a[4], bb[4];
#pragma unroll
      for (int i = 0; i < 4; ++i)
        a[i] = *(const short8_t*)&At[(i * 16 + ml) * BK + ks * 32 + q * 8];
#pragma unroll
      for (int j = 0; j < 4; ++j)
        bb[j] = *(const short8_t*)&Bt[(w * 64 + j * 16 + ml) * BK + ks * 32 + q * 8];
#pragma unroll
      for (int i = 0; i < 4; ++i)
#pragma unroll
        for (int j = 0; j < 4; ++j)
          acc[i][j] = __builtin_amdgcn_mfma_f32_16x16x32_bf16(a[i], bb[j], acc[i][j], 0, 0, 0);
    }
    __syncthreads();
  }

  float* op = out + (long)m0 * D_ + w * 64;
#pragma unroll
  for (int i = 0; i < 4; ++i)
#pragma unroll
    for (int j = 0; j < 4; ++j)
#pragma unroll
      for (int r = 0; r < 4; ++r)
        op[(i * 16 + q * 4 + r) * D_ + j * 16 + ml] = acc[i][j][r];
}

// ---------------------------------------------------------------------------
extern "C" void kernel_launch(void* const* d_in, const int* in_sizes, int n_in,
                              void* d_out, int out_size, void* d_ws, size_t ws_size,
                              hipStream_t stream) {
  const float* feat = (const float*)d_in[0];   // [16384][256]
  const float* adj  = (const float*)d_in[1];   // [16384][16384]
  const float* W    = (const float*)d_in[2];   // [256][512]
  float* out = (float*)d_out;                  // [16384][256]

  char* ws = (char*)d_ws;
  short* featT   = (short*)(ws);               // [256][16384] bf16  : 8 MiB
  short* Wb      = (short*)(ws + (8l << 20));  // [256][512]  bf16  : 256 KiB
  short* neighRM = (short*)(ws + (9l << 20));  // [16384][256] bf16 : 8 MiB
  float* part    = (float*)(ws + (17l << 20)); // [2][16384][256]   : 32 MiB
  float* degp    = (float*)(ws + (49l << 20)); // [2][16384]        : 128 KiB
  // total ws use: ~49.2 MiB

  k_prep<<<dim3(1024 + 32), 256, 0, stream>>>(feat, W, featT, Wb);
  k_main<<<dim3(N_ / BM, KSPLIT), 256, 0, stream>>>(adj, featT, part, degp);
  k_combine<<<dim3(N_ * D_ / 4 / 256), 256, 0, stream>>>(part, degp, neighRM);
  k_out<<<dim3(N_ / BM), 256, 0, stream>>>(feat, neighRM, Wb, out);
}